// Round 5
// baseline (35.969 us; speedup 1.0000x reference)
//
#include <hip/hip_runtime.h>

constexpr int B   = 1024;
constexpr int N   = 4096;
constexpr int BLK = 256;                 // 4 waves; one n per thread
constexpr int BLOCKS_PER_BATCH = N / BLK;            // 16
constexpr int WAVES_PER_BATCH  = BLOCKS_PER_BATCH * (BLK / 64);  // 64
constexpr float C01 = 0.4082482904638630f;  // sqrt(0.5)/sqrt(3)
constexpr float C11 = 0.2886751345948129f;  // sqrt(0.5)/sqrt(6)

typedef float f32x4 __attribute__((ext_vector_type(4)));

// Stage 1: grid = B*16 blocks x 256 threads, one n per thread.
// edge_attr staged through LDS via dense float4 loads; feats read dense NT.
__global__ __launch_bounds__(BLK) void tp_reduce_kernel(
    const float* __restrict__ feats,      // (B, N, 8)
    const float* __restrict__ edge_attr,  // (B, N, 3)
    const float* __restrict__ w_path0,    // (5,)
    const float* __restrict__ w_path1,    // (1,)
    float* __restrict__ part)             // (B*64, 3) per-wave partials
{
    const int blk = blockIdx.x;
    const int b   = blk >> 4;
    const int q   = blk & 15;
    const int t   = threadIdx.x;
    const long base = (long)b * N + (q << 8);   // first n of this chunk

    // --- dense cooperative edge load: 256*3 floats = 192 float4 ---
    __shared__ float esh[BLK * 3];
    const f32x4* ev = reinterpret_cast<const f32x4*>(edge_attr + base * 3);
    if (t < (BLK * 3) / 4) {
        reinterpret_cast<f32x4*>(esh)[t] = ev[t];
    }

    // --- feats: 32 contiguous bytes per lane -> two dense float4 (NT) ---
    const f32x4* fp = reinterpret_cast<const f32x4*>(feats + (base + t) * 8);
    f32x4 f0 = __builtin_nontemporal_load(fp);
    f32x4 f1 = __builtin_nontemporal_load(fp + 1);

    __syncthreads();

    const float e0 = esh[3 * t + 0];
    const float e1 = esh[3 * t + 1];
    const float e2 = esh[3 * t + 2];

    const float s = f0.x * w_path0[0] + f0.y * w_path0[1] + f0.z * w_path0[2]
                  + f0.w * w_path0[3] + f1.x * w_path0[4];
    const float c01s = C01 * s;
    const float c11w = C11 * w_path1[0];
    const float v0 = f1.y, v1 = f1.z, v2 = f1.w;

    float t0 = c01s * e0 + c11w * (v1 * e2 - v2 * e1);
    float t1 = c01s * e1 + c11w * (v2 * e0 - v0 * e2);
    float t2 = c01s * e2 + c11w * (v0 * e1 - v1 * e0);

    #pragma unroll
    for (int off = 32; off > 0; off >>= 1) {
        t0 += __shfl_down(t0, off);
        t1 += __shfl_down(t1, off);
        t2 += __shfl_down(t2, off);
    }

    if ((t & 63) == 0) {
        const int w = (q << 2) + (t >> 6);   // wave index within batch, 0..63
        float* p = part + ((long)b * WAVES_PER_BATCH + w) * 3;
        p[0] = t0;
        p[1] = t1;
        p[2] = t2;
    }
}

// Stage 2: one wave per batch. Sum 64 partials, then MLP 3->128(relu)->3.
__global__ __launch_bounds__(64) void mlp_kernel(
    const float* __restrict__ part,  // (B*64, 3)
    const float* __restrict__ W1,    // (3, 128)
    const float* __restrict__ b1,    // (128,)
    const float* __restrict__ W2,    // (128, 3)
    const float* __restrict__ b2,    // (3,)
    float* __restrict__ out)         // (B, 3)
{
    const int b = blockIdx.x;
    const int l = threadIdx.x;  // 0..63

    const float* p = part + ((long)b * WAVES_PER_BATCH + l) * 3;
    float a0 = p[0], a1 = p[1], a2 = p[2];

    #pragma unroll
    for (int off = 32; off > 0; off >>= 1) {
        a0 += __shfl_down(a0, off);
        a1 += __shfl_down(a1, off);
        a2 += __shfl_down(a2, off);
    }
    const float g0 = __shfl(a0, 0) * (1.0f / (float)N);
    const float g1 = __shfl(a1, 0) * (1.0f / (float)N);
    const float g2 = __shfl(a2, 0) * (1.0f / (float)N);

    float p0 = 0.0f, p1 = 0.0f, p2 = 0.0f;
    #pragma unroll
    for (int half = 0; half < 2; ++half) {
        const int j = l + half * 64;
        float h = b1[j] + g0 * W1[j] + g1 * W1[128 + j] + g2 * W1[256 + j];
        h = fmaxf(h, 0.0f);
        p0 += h * W2[j * 3 + 0];
        p1 += h * W2[j * 3 + 1];
        p2 += h * W2[j * 3 + 2];
    }
    #pragma unroll
    for (int off = 32; off > 0; off >>= 1) {
        p0 += __shfl_down(p0, off);
        p1 += __shfl_down(p1, off);
        p2 += __shfl_down(p2, off);
    }
    if (l == 0) {
        float* o = out + (long)b * 3;
        o[0] = p0 + b2[0];
        o[1] = p1 + b2[1];
        o[2] = p2 + b2[2];
    }
}

extern "C" void kernel_launch(void* const* d_in, const int* in_sizes, int n_in,
                              void* d_out, int out_size, void* d_ws, size_t ws_size,
                              hipStream_t stream) {
    const float* feats     = (const float*)d_in[0];
    const float* edge_attr = (const float*)d_in[1];
    const float* w_path0   = (const float*)d_in[2];
    const float* w_path1   = (const float*)d_in[3];
    const float* W1        = (const float*)d_in[4];
    const float* b1        = (const float*)d_in[5];
    const float* W2        = (const float*)d_in[6];
    const float* b2        = (const float*)d_in[7];
    float* out = (float*)d_out;

    float* part = (float*)d_ws;  // B*64*3 floats = 768 KiB

    tp_reduce_kernel<<<B * BLOCKS_PER_BATCH, BLK, 0, stream>>>(
        feats, edge_attr, w_path0, w_path1, part);
    mlp_kernel<<<B, 64, 0, stream>>>(part, W1, b1, W2, b2, out);
}